// Round 1
// baseline (504.159 us; speedup 1.0000x reference)
//
#include <hip/hip_runtime.h>

#define HW      4096      // 64*64
#define W_DIM   64
#define C_IN    256
#define C_COMP  64
#define NK      25        // 5x5 taps
// pixel-shuffle: channel ch = k*4 + q, q = i*2 + j  (SIG=2)

// ---------------------------------------------------------------------------
// Kernel 0: transpose encoder weights to wT[q][c][tap][32] (k contiguous,
// padded to 32 floats for 16B-aligned float4 loads).
// w_enc layout: [ch=k*4+q][c=64][ti=3][tj=3]
__global__ __launch_bounds__(256) void k_wtrans(const float* __restrict__ wenc,
                                                float* __restrict__ wt) {
    int idx = blockIdx.x * 256 + threadIdx.x;   // 4*64*9*25 = 57600
    if (idx >= 57600) return;
    int k = idx % 25; int rest = idx / 25;
    int tap = rest % 9; rest /= 9;
    int c = rest % 64; int q = rest / 64;
    wt[(((q * 64 + c) * 9 + tap) << 5) + k] = wenc[((k * 4 + q) * 64 + c) * 9 + tap];
}

// ---------------------------------------------------------------------------
// Kernel 1: 1x1 conv (channel compressor). C[n][cc][p] = sum_c W[cc][c]*x[n][c][p]
// block: 256 threads = 64 pixels x 4 cc-groups (16 cc each). grid: (4096/64, 4)
__global__ __launch_bounds__(256) void k_compress(const float* __restrict__ x,
        const float* __restrict__ w, const float* __restrict__ b,
        float* __restrict__ comp) {
    int n = blockIdx.y;
    int tid = threadIdx.x;
    int px = tid & 63;
    int cg = tid >> 6;
    int p = blockIdx.x * 64 + px;
    int ccb = cg * 16;
    const float* xp = x + (size_t)n * C_IN * HW + p;
    float acc[16];
#pragma unroll
    for (int i = 0; i < 16; ++i) acc[i] = b[ccb + i];
    for (int c = 0; c < C_IN; c += 4) {
        float xv0 = xp[(size_t)(c + 0) * HW];
        float xv1 = xp[(size_t)(c + 1) * HW];
        float xv2 = xp[(size_t)(c + 2) * HW];
        float xv3 = xp[(size_t)(c + 3) * HW];
#pragma unroll
        for (int i = 0; i < 16; ++i) {
            const float4 wv = *(const float4*)(w + (ccb + i) * C_IN + c);
            acc[i] = fmaf(wv.x, xv0, acc[i]);
            acc[i] = fmaf(wv.y, xv1, acc[i]);
            acc[i] = fmaf(wv.z, xv2, acc[i]);
            acc[i] = fmaf(wv.w, xv3, acc[i]);
        }
    }
    float* op = comp + (size_t)n * C_COMP * HW + p;
#pragma unroll
    for (int i = 0; i < 16; ++i) op[(size_t)(ccb + i) * HW] = acc[i];
}

// ---------------------------------------------------------------------------
// Kernel 2: 3x3 conv (64 -> 100 ch) + fused pixel-shuffle softmax over k=25.
// block: 256 threads = 64 pixels (16w x 4h) x 4 q. grid: (64 tiles, 4 n)
// mask output layout: [n][kq=100][p]  (kq = k*4+q)
__global__ __launch_bounds__(256) void k_enc_softmax(const float* __restrict__ comp,
        const float* __restrict__ wt, const float* __restrict__ benc,
        float* __restrict__ mask) {
    int n = blockIdx.y;
    int tile = blockIdx.x;
    int tx = tile & 3, ty = tile >> 2;          // 4 x-tiles(16w), 16 y-tiles(4h)
    int tid = threadIdx.x;
    int px = tid & 15, py = (tid >> 4) & 3, q = tid >> 6;
    int wx = tx * 16 + px, hy = ty * 4 + py;

    float acc[NK];
#pragma unroll
    for (int k = 0; k < NK; ++k) acc[k] = benc[k * 4 + q];

    // clamped coords + border zero-flags (branchless padding)
    int hcl[3], wcl[3];
    float tf[9];
#pragma unroll
    for (int d = 0; d < 3; ++d) {
        hcl[d] = min(max(hy + d - 1, 0), 63);
        wcl[d] = min(max(wx + d - 1, 0), 63);
    }
#pragma unroll
    for (int ti = 0; ti < 3; ++ti)
#pragma unroll
        for (int tj = 0; tj < 3; ++tj) {
            bool inb = ((unsigned)(hy + ti - 1) < 64u) && ((unsigned)(wx + tj - 1) < 64u);
            tf[ti * 3 + tj] = inb ? 1.0f : 0.0f;
        }

    const float* cbase = comp + (size_t)n * C_COMP * HW;
    const float* wq = wt + (size_t)q * C_COMP * 9 * 32;
    for (int c = 0; c < C_COMP; ++c) {
        const float* cc = cbase + (size_t)c * HW;
#pragma unroll
        for (int ti = 0; ti < 3; ++ti) {
#pragma unroll
            for (int tj = 0; tj < 3; ++tj) {
                float val = cc[hcl[ti] * W_DIM + wcl[tj]] * tf[ti * 3 + tj];
                const float* wp = wq + ((size_t)(c * 9 + ti * 3 + tj)) * 32;
#pragma unroll
                for (int kk = 0; kk < 6; ++kk) {
                    float4 wv = *(const float4*)(wp + kk * 4);
                    acc[kk * 4 + 0] = fmaf(wv.x, val, acc[kk * 4 + 0]);
                    acc[kk * 4 + 1] = fmaf(wv.y, val, acc[kk * 4 + 1]);
                    acc[kk * 4 + 2] = fmaf(wv.z, val, acc[kk * 4 + 2]);
                    acc[kk * 4 + 3] = fmaf(wv.w, val, acc[kk * 4 + 3]);
                }
                acc[24] = fmaf(wp[24], val, acc[24]);
            }
        }
    }
    // softmax over 25 taps
    float m = acc[0];
#pragma unroll
    for (int k = 1; k < NK; ++k) m = fmaxf(m, acc[k]);
    float s = 0.f;
#pragma unroll
    for (int k = 0; k < NK; ++k) { acc[k] = __expf(acc[k] - m); s += acc[k]; }
    float inv = 1.0f / s;
    int p = hy * W_DIM + wx;
    float* mp = mask + ((size_t)n * 100 + q) * HW + p;
#pragma unroll
    for (int k = 0; k < NK; ++k) mp[(size_t)(k * 4) * HW] = acc[k] * inv;
}

// ---------------------------------------------------------------------------
// Kernel 3: CARAFE reassembly. out[n][c][2h+i][2w+j] = sum_k mask[k*4+i*2+j] * xpad
// block: 256 threads = 64 pixels (16w x 4h) x 2 i-groups x 2 c-subgroups(32c).
// grid: (64 tiles, 4 c-groups of 64, 4 n) = 1024 blocks.
__global__ __launch_bounds__(256) void k_reassemble(const float* __restrict__ x,
        const float* __restrict__ mask, float* __restrict__ out) {
    int n = blockIdx.z;
    int cgrp = blockIdx.y;
    int tile = blockIdx.x;
    int tx = tile & 3, ty = tile >> 2;
    int tid = threadIdx.x;
    int px = tid & 15, py = (tid >> 4) & 3;
    int ig = (tid >> 6) & 1, cs = tid >> 7;
    int wx = tx * 16 + px, hy = ty * 4 + py;
    int p = hy * W_DIM + wx;

    // load this thread's 50 mask values (q = ig*2, ig*2+1); fold zero-pad into mask
    const float* mp = mask + (size_t)n * 100 * HW + p;
    float m0[NK], m1[NK];
    int off[NK];
#pragma unroll
    for (int k = 0; k < NK; ++k) {
        int di = k / 5, dj = k % 5;
        bool inb = ((unsigned)(hy + di - 2) < 64u) && ((unsigned)(wx + dj - 2) < 64u);
        float f = inb ? 1.0f : 0.0f;
        m0[k] = mp[(size_t)(k * 4 + ig * 2 + 0) * HW] * f;
        m1[k] = mp[(size_t)(k * 4 + ig * 2 + 1) * HW] * f;
        int hc = min(max(hy + di - 2, 0), 63);
        int wc = min(max(wx + dj - 2, 0), 63);
        off[k] = hc * W_DIM + wc;
    }

    int c0 = cgrp * 64 + cs * 32;
    const float* xb = x + ((size_t)n * C_IN + c0) * HW;
    float* ob = out + ((size_t)(n * C_IN + c0) * 128 + (2 * hy + ig)) * 128 + 2 * wx;
    for (int c = 0; c < 32; ++c) {
        const float* xc = xb + (size_t)c * HW;
        float a0 = 0.f, a1 = 0.f;
#pragma unroll
        for (int k = 0; k < NK; ++k) {
            float xv = xc[off[k]];
            a0 = fmaf(m0[k], xv, a0);
            a1 = fmaf(m1[k], xv, a1);
        }
        *(float2*)(ob + (size_t)c * 128 * 128) = make_float2(a0, a1);
    }
}

// ---------------------------------------------------------------------------
extern "C" void kernel_launch(void* const* d_in, const int* in_sizes, int n_in,
                              void* d_out, int out_size, void* d_ws, size_t ws_size,
                              hipStream_t stream) {
    const float* x      = (const float*)d_in[0];
    const float* w_comp = (const float*)d_in[1];
    const float* b_comp = (const float*)d_in[2];
    const float* w_enc  = (const float*)d_in[3];
    const float* b_enc  = (const float*)d_in[4];
    float* out = (float*)d_out;
    float* ws  = (float*)d_ws;

    float* comp = ws;                        // 4*64*4096      = 1,048,576 f
    float* mask = ws + 1048576;              // 4*100*4096     = 1,638,400 f
    float* wt   = ws + 1048576 + 1638400;    // 4*64*9*32      =    73,728 f

    hipLaunchKernelGGL(k_wtrans,      dim3(226),       dim3(256), 0, stream, w_enc, wt);
    hipLaunchKernelGGL(k_compress,    dim3(64, 4),     dim3(256), 0, stream, x, w_comp, b_comp, comp);
    hipLaunchKernelGGL(k_enc_softmax, dim3(64, 4),     dim3(256), 0, stream, comp, wt, b_enc, mask);
    hipLaunchKernelGGL(k_reassemble,  dim3(64, 4, 4),  dim3(256), 0, stream, x, mask, out);
}

// Round 2
// 311.200 us; speedup vs baseline: 1.6200x; 1.6200x over previous
//
#include <hip/hip_runtime.h>

#define HW      4096      // 64*64
#define W_DIM   64
#define C_IN    256
#define C_COMP  64
#define NK      25        // 5x5 taps
#define NQ      112       // kq padded 100 -> 112

typedef __bf16 bf16x8 __attribute__((ext_vector_type(8)));
typedef float  f32x4  __attribute__((ext_vector_type(4)));

static __device__ __forceinline__ unsigned short f2bf(float f) {
    unsigned x = __float_as_uint(f);
    unsigned r = (x + 0x7fffu + ((x >> 16) & 1u)) >> 16;   // RNE
    return (unsigned short)r;
}

// ---------------------------------------------------------------------------
// Kernel 0: encoder weights -> bf16 wtb[tap][kq(112, zero-pad)][c=64]
// w_enc layout: [ch=kq(100)][c=64][tap=9]
__global__ __launch_bounds__(256) void k_wtrans(const float* __restrict__ wenc,
                                                unsigned short* __restrict__ wtb) {
    int idx = blockIdx.x * 256 + threadIdx.x;   // 9*112*64 = 64512
    if (idx >= 64512) return;
    int c = idx & 63;
    int t2 = idx >> 6;
    int kq = t2 % NQ;
    int tap = t2 / NQ;
    float v = (kq < 100) ? wenc[(kq * 64 + c) * 9 + tap] : 0.0f;
    wtb[idx] = f2bf(v);
}

// ---------------------------------------------------------------------------
// Kernel 1: 1x1 conv (channel compressor), fp32 math, bf16 out [n][p][cc=64].
// Weights made wave-uniform (readfirstlane) -> s_load through scalar cache.
__global__ __launch_bounds__(256) void k_compress(const float* __restrict__ x,
        const float* __restrict__ w, const float* __restrict__ b,
        unsigned short* __restrict__ compb) {
    int n = blockIdx.y;
    int tid = threadIdx.x;
    int px = tid & 63;
    int cg = __builtin_amdgcn_readfirstlane(tid >> 6);   // wave-uniform
    int p = blockIdx.x * 64 + px;
    int ccb = cg * 16;
    const float* xp = x + (size_t)n * C_IN * HW + p;
    float acc[16];
#pragma unroll
    for (int i = 0; i < 16; ++i) acc[i] = b[ccb + i];
    for (int c = 0; c < C_IN; c += 4) {
        float xv0 = xp[(size_t)(c + 0) * HW];
        float xv1 = xp[(size_t)(c + 1) * HW];
        float xv2 = xp[(size_t)(c + 2) * HW];
        float xv3 = xp[(size_t)(c + 3) * HW];
#pragma unroll
        for (int i = 0; i < 16; ++i) {
            const float4 wv = *(const float4*)(w + (ccb + i) * C_IN + c);  // uniform -> s_load
            acc[i] = fmaf(wv.x, xv0, acc[i]);
            acc[i] = fmaf(wv.y, xv1, acc[i]);
            acc[i] = fmaf(wv.z, xv2, acc[i]);
            acc[i] = fmaf(wv.w, xv3, acc[i]);
        }
    }
    unsigned short hb[16];
#pragma unroll
    for (int i = 0; i < 16; ++i) hb[i] = f2bf(acc[i]);
    unsigned short* op = compb + ((size_t)n * HW + p) * 64 + ccb;
    *(uint4*)(op + 0) = *(uint4*)(hb + 0);
    *(uint4*)(op + 8) = *(uint4*)(hb + 8);
}

// ---------------------------------------------------------------------------
// Kernel 2: MFMA 3x3 conv (64->100) + fused pixel-shuffle softmax.
// GEMM: M = 16x16 px tile, N = 112 kq, K = 576 = 9 taps x 64 c.
// Block: 256 thr / 4 waves; wave = rows 4w..4w+3 (4 M-tiles) x 7 N-tiles.
// LDS: comp halo tile 18x18 px x 144B (64c bf16, pad to 72) = 46656 B
//      B panel [112][144B] = 16128 B (single buffer, register-prefetched)
//      epilogue union: 4 waves x 32px x 113 f32 = 57856 B (reuses both)
#define CSTRIDE 144          // bytes per pixel row in LDS (72 bf16 slots)
#define SB_OFF  46656
#define EPI_PAD 113
__global__ __launch_bounds__(256) void k_enc_mfma(
        const unsigned short* __restrict__ compb,
        const unsigned short* __restrict__ wtb,
        const float* __restrict__ benc,
        float* __restrict__ mask) {
    __shared__ __align__(16) unsigned char smem[SB_OFF + 16128];  // 62784 B
    __shared__ float sbias[NQ];

    int n = blockIdx.y;
    int tile = blockIdx.x;
    int h0 = (tile >> 2) * 16, w0 = (tile & 3) * 16;
    int tid = threadIdx.x;
    int wv = tid >> 6, lane = tid & 63;
    int l15 = lane & 15, l4 = lane >> 4;

    if (tid < NQ) sbias[tid] = (tid < 100) ? benc[tid] : 0.0f;

    // ---- stage comp halo tile: 324 px x 128 B (zero outside image) ----
    const uint4* csrc = (const uint4*)(compb + (size_t)n * HW * 64);
#pragma unroll
    for (int pass = 0; pass < 11; ++pass) {
        int slot = pass * 256 + tid;             // 324*8 = 2592 slots
        if (slot < 2592) {
            int pxi = slot >> 3, j = slot & 7;
            int r = pxi / 18, cl = pxi % 18;
            int gh = h0 + r - 1, gw = w0 + cl - 1;
            uint4 v = make_uint4(0u, 0u, 0u, 0u);
            if ((unsigned)gh < 64u && (unsigned)gw < 64u)
                v = csrc[(size_t)(gh * 64 + gw) * 8 + j];
            *(uint4*)(smem + (size_t)pxi * CSTRIDE + j * 16) = v;
        }
    }
    // ---- stage B panel for tap 0 ----
    {
        const uint4* bsrc = (const uint4*)(wtb);
#pragma unroll
        for (int pass = 0; pass < 4; ++pass) {
            int slot = pass * 256 + tid;         // 112*8 = 896 slots
            if (slot < 896) {
                int kq = slot >> 3, j = slot & 7;
                *(uint4*)(smem + SB_OFF + kq * CSTRIDE + j * 16) = bsrc[slot];
            }
        }
    }
    __syncthreads();

    f32x4 acc[4][7];
#pragma unroll
    for (int s = 0; s < 4; ++s)
#pragma unroll
        for (int nt = 0; nt < 7; ++nt) acc[s][nt] = (f32x4){0.f, 0.f, 0.f, 0.f};

    for (int tap = 0; tap < 9; ++tap) {
        // prefetch next tap's B panel into regs (hidden under the mfma loop)
        uint4 pre[4];
        if (tap < 8) {
            const uint4* bsrc = (const uint4*)(wtb + (size_t)(tap + 1) * NQ * 64);
#pragma unroll
            for (int pass = 0; pass < 4; ++pass) {
                int slot = pass * 256 + tid;
                if (slot < 896) pre[pass] = bsrc[slot];
            }
        }
        int ti = tap / 3, tj = tap % 3;
#pragma unroll
        for (int ck = 0; ck < 2; ++ck) {
            bf16x8 af[4], bfr[7];
            int koff = (ck * 32 + l4 * 8) * 2;
#pragma unroll
            for (int s = 0; s < 4; ++s)
                af[s] = *(const bf16x8*)(smem +
                        (size_t)((4 * wv + s + ti) * 18 + l15 + tj) * CSTRIDE + koff);
#pragma unroll
            for (int nt = 0; nt < 7; ++nt)
                bfr[nt] = *(const bf16x8*)(smem + SB_OFF +
                        (size_t)(nt * 16 + l15) * CSTRIDE + koff);
#pragma unroll
            for (int s = 0; s < 4; ++s)
#pragma unroll
                for (int nt = 0; nt < 7; ++nt)
                    acc[s][nt] = __builtin_amdgcn_mfma_f32_16x16x32_bf16(
                            af[s], bfr[nt], acc[s][nt], 0, 0, 0);
        }
        __syncthreads();   // everyone done reading B panel
        if (tap < 8) {
#pragma unroll
            for (int pass = 0; pass < 4; ++pass) {
                int slot = pass * 256 + tid;
                if (slot < 896) {
                    int kq = slot >> 3, j = slot & 7;
                    *(uint4*)(smem + SB_OFF + kq * CSTRIDE + j * 16) = pre[pass];
                }
            }
        }
        __syncthreads();
    }

    // ---- epilogue: per-wave LDS transpose + softmax over 25 taps ----
    float* smE = (float*)smem + (size_t)wv * 32 * EPI_PAD;   // 4 x 14464 B
    float* maskn = mask + (size_t)n * 100 * HW;
#pragma unroll
    for (int c2 = 0; c2 < 2; ++c2) {
#pragma unroll
        for (int half = 0; half < 2; ++half) {
            int s = c2 * 2 + half;
#pragma unroll
            for (int nt = 0; nt < 7; ++nt) {
                f32x4 v = acc[s][nt];
#pragma unroll
                for (int reg = 0; reg < 4; ++reg) {
                    int pxl = half * 16 + (l4 * 4 + reg);
                    smE[pxl * EPI_PAD + nt * 16 + l15] = v[reg];
                }
            }
        }
        __syncthreads();
#pragma unroll
        for (int it = 0; it < 2; ++it) {
            int q = it * 2 + (lane >> 5);
            int pxl = lane & 31;
            const float* row = smE + pxl * EPI_PAD;
            float v[NK], mx = -1e30f;
#pragma unroll
            for (int k = 0; k < NK; ++k) {
                v[k] = row[4 * k + q] + sbias[4 * k + q];
                mx = fmaxf(mx, v[k]);
            }
            float ssum = 0.f;
#pragma unroll
            for (int k = 0; k < NK; ++k) { v[k] = __expf(v[k] - mx); ssum += v[k]; }
            float inv = 1.0f / ssum;
            int half = pxl >> 4, pcol = pxl & 15;
            int R = 4 * wv + c2 * 2 + half;
            size_t p = (size_t)(h0 + R) * 64 + w0 + pcol;
            float* mp = maskn + p;
#pragma unroll
            for (int k = 0; k < NK; ++k) mp[(size_t)(4 * k + q) * HW] = v[k] * inv;
        }
        __syncthreads();
    }
}

// ---------------------------------------------------------------------------
// Kernel 3: CARAFE reassembly (unchanged from R0 — profile next round).
__global__ __launch_bounds__(256) void k_reassemble(const float* __restrict__ x,
        const float* __restrict__ mask, float* __restrict__ out) {
    int n = blockIdx.z;
    int cgrp = blockIdx.y;
    int tile = blockIdx.x;
    int tx = tile & 3, ty = tile >> 2;
    int tid = threadIdx.x;
    int px = tid & 15, py = (tid >> 4) & 3;
    int ig = (tid >> 6) & 1, cs = tid >> 7;
    int wx = tx * 16 + px, hy = ty * 4 + py;
    int p = hy * W_DIM + wx;

    const float* mp = mask + (size_t)n * 100 * HW + p;
    float m0[NK], m1[NK];
    int off[NK];
#pragma unroll
    for (int k = 0; k < NK; ++k) {
        int di = k / 5, dj = k % 5;
        bool inb = ((unsigned)(hy + di - 2) < 64u) && ((unsigned)(wx + dj - 2) < 64u);
        float f = inb ? 1.0f : 0.0f;
        m0[k] = mp[(size_t)(k * 4 + ig * 2 + 0) * HW] * f;
        m1[k] = mp[(size_t)(k * 4 + ig * 2 + 1) * HW] * f;
        int hc = min(max(hy + di - 2, 0), 63);
        int wc = min(max(wx + dj - 2, 0), 63);
        off[k] = hc * W_DIM + wc;
    }

    int c0 = cgrp * 64 + cs * 32;
    const float* xb = x + ((size_t)n * C_IN + c0) * HW;
    float* ob = out + ((size_t)(n * C_IN + c0) * 128 + (2 * hy + ig)) * 128 + 2 * wx;
    for (int c = 0; c < 32; ++c) {
        const float* xc = xb + (size_t)c * HW;
        float a0 = 0.f, a1 = 0.f;
#pragma unroll
        for (int k = 0; k < NK; ++k) {
            float xv = xc[off[k]];
            a0 = fmaf(m0[k], xv, a0);
            a1 = fmaf(m1[k], xv, a1);
        }
        *(float2*)(ob + (size_t)c * 128 * 128) = make_float2(a0, a1);
    }
}

// ---------------------------------------------------------------------------
extern "C" void kernel_launch(void* const* d_in, const int* in_sizes, int n_in,
                              void* d_out, int out_size, void* d_ws, size_t ws_size,
                              hipStream_t stream) {
    const float* x      = (const float*)d_in[0];
    const float* w_comp = (const float*)d_in[1];
    const float* b_comp = (const float*)d_in[2];
    const float* w_enc  = (const float*)d_in[3];
    const float* b_enc  = (const float*)d_in[4];
    float* out = (float*)d_out;
    unsigned char* ws = (unsigned char*)d_ws;

    unsigned short* compb = (unsigned short*)(ws);              // 4*4096*64*2  = 2,097,152 B
    unsigned short* wtb   = (unsigned short*)(ws + 2097152);    // 9*112*64*2   =   129,024 B
    float*          mask  = (float*)(ws + 2097152 + 129024);    // 4*100*4096*4 = 6,553,600 B

    hipLaunchKernelGGL(k_wtrans,     dim3(252),      dim3(256), 0, stream, w_enc, wtb);
    hipLaunchKernelGGL(k_compress,   dim3(64, 4),    dim3(256), 0, stream, x, w_comp, b_comp, compb);
    hipLaunchKernelGGL(k_enc_mfma,   dim3(16, 4),    dim3(256), 0, stream, compb, wtb, b_enc, mask);
    hipLaunchKernelGGL(k_reassemble, dim3(64, 4, 4), dim3(256), 0, stream, x, mask, out);
}

// Round 3
// 179.163 us; speedup vs baseline: 2.8140x; 1.7370x over previous
//
#include <hip/hip_runtime.h>

#define HW      4096      // 64*64
#define W_DIM   64
#define C_IN    256
#define C_COMP  64
#define NK      25        // 5x5 taps
#define NQ      112       // kq padded 100 -> 112

typedef __bf16 bf16x8 __attribute__((ext_vector_type(8)));
typedef float  f32x4  __attribute__((ext_vector_type(4)));

static __device__ __forceinline__ unsigned short f2bf(float f) {
    unsigned x = __float_as_uint(f);
    unsigned r = (x + 0x7fffu + ((x >> 16) & 1u)) >> 16;   // RNE
    return (unsigned short)r;
}

// ---------------------------------------------------------------------------
// Kernel 0: encoder weights -> bf16 wtb[tap][kq(112, zero-pad)][c=64]
__global__ __launch_bounds__(256) void k_wtrans(const float* __restrict__ wenc,
                                                unsigned short* __restrict__ wtb) {
    int idx = blockIdx.x * 256 + threadIdx.x;   // 9*112*64 = 64512
    if (idx >= 64512) return;
    int c = idx & 63;
    int t2 = idx >> 6;
    int kq = t2 % NQ;
    int tap = t2 / NQ;
    float v = (kq < 100) ? wenc[(kq * 64 + c) * 9 + tap] : 0.0f;
    wtb[idx] = f2bf(v);
}

// ---------------------------------------------------------------------------
// Kernel 1: 1x1 conv, fp32 math, bf16 out [n][p][cc=64]. c-unroll 8 for MLP.
__global__ __launch_bounds__(256) void k_compress(const float* __restrict__ x,
        const float* __restrict__ w, const float* __restrict__ b,
        unsigned short* __restrict__ compb) {
    int n = blockIdx.y;
    int tid = threadIdx.x;
    int px = tid & 63;
    int cg = __builtin_amdgcn_readfirstlane(tid >> 6);   // wave-uniform
    int p = blockIdx.x * 64 + px;
    int ccb = cg * 16;
    const float* xp = x + (size_t)n * C_IN * HW + p;
    float acc[16];
#pragma unroll
    for (int i = 0; i < 16; ++i) acc[i] = b[ccb + i];
    for (int c = 0; c < C_IN; c += 8) {
        float xv[8];
#pragma unroll
        for (int u = 0; u < 8; ++u) xv[u] = xp[(size_t)(c + u) * HW];
#pragma unroll
        for (int i = 0; i < 16; ++i) {
            const float4 w0 = *(const float4*)(w + (ccb + i) * C_IN + c);      // s_load
            const float4 w1 = *(const float4*)(w + (ccb + i) * C_IN + c + 4);
            acc[i] = fmaf(w0.x, xv[0], acc[i]);
            acc[i] = fmaf(w0.y, xv[1], acc[i]);
            acc[i] = fmaf(w0.z, xv[2], acc[i]);
            acc[i] = fmaf(w0.w, xv[3], acc[i]);
            acc[i] = fmaf(w1.x, xv[4], acc[i]);
            acc[i] = fmaf(w1.y, xv[5], acc[i]);
            acc[i] = fmaf(w1.z, xv[6], acc[i]);
            acc[i] = fmaf(w1.w, xv[7], acc[i]);
        }
    }
    unsigned short hb[16];
#pragma unroll
    for (int i = 0; i < 16; ++i) hb[i] = f2bf(acc[i]);
    unsigned short* op = compb + ((size_t)n * HW + p) * 64 + ccb;
    *(uint4*)(op + 0) = *(uint4*)(hb + 0);
    *(uint4*)(op + 8) = *(uint4*)(hb + 8);
}

// ---------------------------------------------------------------------------
// Kernel 2: MFMA 3x3 conv (64->100) + fused softmax. 8x8 px tiles, 256 blocks.
// GEMM: M = 64 px (4 waves x 1 Mtile), N = 112 kq (7 Ntiles), K = 576.
// mask output layout: [n][p][kq=100]  (kq contiguous!)
#define CSTRIDE 144          // bytes per px record in LDS (64c bf16 + 8 pad)
#define SB_OFF  14400        // 100 px * 144
#define EPI_OFF 30528        // SB_OFF + 112*144
#define EPI_PAD 116          // floats per px row (100 used, %4==0 for b128)
__global__ __launch_bounds__(256) void k_enc_mfma(
        const unsigned short* __restrict__ compb,
        const unsigned short* __restrict__ wtb,
        const float* __restrict__ benc,
        float* __restrict__ mask) {
    __shared__ __align__(16) unsigned char smem[EPI_OFF + 4 * 16 * EPI_PAD * 4]; // 60224 B
    __shared__ float sbias[NQ];

    int n = blockIdx.y;
    int tile = blockIdx.x;                       // 64 tiles of 8x8
    int h0 = (tile >> 3) * 8, w0 = (tile & 7) * 8;
    int tid = threadIdx.x;
    int wv = tid >> 6, lane = tid & 63;
    int l15 = lane & 15, l4 = lane >> 4;

    if (tid < NQ) sbias[tid] = (tid < 100) ? benc[tid] : 0.0f;

    // ---- stage comp halo tile: 10x10 px x 128 B (zero outside image) ----
    const uint4* csrc = (const uint4*)(compb + (size_t)n * HW * 64);
#pragma unroll
    for (int pass = 0; pass < 4; ++pass) {
        int slot = pass * 256 + tid;             // 100*8 = 800 slots
        if (slot < 800) {
            int pxi = slot >> 3, j = slot & 7;
            int gh = h0 + pxi / 10 - 1, gw = w0 + pxi % 10 - 1;
            uint4 v = make_uint4(0u, 0u, 0u, 0u);
            if ((unsigned)gh < 64u && (unsigned)gw < 64u)
                v = csrc[(size_t)(gh * 64 + gw) * 8 + j];
            *(uint4*)(smem + (size_t)pxi * CSTRIDE + j * 16) = v;
        }
    }
    // ---- stage B panel for tap 0 ----
    {
        const uint4* bsrc = (const uint4*)(wtb);
#pragma unroll
        for (int pass = 0; pass < 4; ++pass) {
            int slot = pass * 256 + tid;         // 112*8 = 896 slots
            if (slot < 896) {
                int kq = slot >> 3, j = slot & 7;
                *(uint4*)(smem + SB_OFF + kq * CSTRIDE + j * 16) = bsrc[slot];
            }
        }
    }
    __syncthreads();

    f32x4 acc[7];
#pragma unroll
    for (int nt = 0; nt < 7; ++nt) acc[nt] = (f32x4){0.f, 0.f, 0.f, 0.f};

    int r_t = 2 * wv + (l15 >> 3);               // tile-local row of A fragment
    int cl  = l15 & 7;

    for (int tap = 0; tap < 9; ++tap) {
        uint4 pre[4];
        if (tap < 8) {
            const uint4* bsrc = (const uint4*)(wtb + (size_t)(tap + 1) * NQ * 64);
#pragma unroll
            for (int pass = 0; pass < 4; ++pass) {
                int slot = pass * 256 + tid;
                if (slot < 896) pre[pass] = bsrc[slot];
            }
        }
        int ti = tap / 3, tj = tap % 3;
        int apx = (r_t + ti) * 10 + (cl + tj);   // halo px index (origin -1 baked)
#pragma unroll
        for (int ck = 0; ck < 2; ++ck) {
            int koff = (ck * 32 + l4 * 8) * 2;
            bf16x8 af = *(const bf16x8*)(smem + (size_t)apx * CSTRIDE + koff);
            bf16x8 bfr[7];
#pragma unroll
            for (int nt = 0; nt < 7; ++nt)
                bfr[nt] = *(const bf16x8*)(smem + SB_OFF +
                        (size_t)(nt * 16 + l15) * CSTRIDE + koff);
#pragma unroll
            for (int nt = 0; nt < 7; ++nt)
                acc[nt] = __builtin_amdgcn_mfma_f32_16x16x32_bf16(
                        af, bfr[nt], acc[nt], 0, 0, 0);
        }
        __syncthreads();
        if (tap < 8) {
#pragma unroll
            for (int pass = 0; pass < 4; ++pass) {
                int slot = pass * 256 + tid;
                if (slot < 896) {
                    int kq = slot >> 3, j = slot & 7;
                    *(uint4*)(smem + SB_OFF + kq * CSTRIDE + j * 16) = pre[pass];
                }
            }
        }
        __syncthreads();
    }

    // ---- epilogue: per-wave region, no cross-wave barriers needed ----
    float* smE = (float*)(smem + EPI_OFF) + (size_t)wv * 16 * EPI_PAD;
    float* maskn = mask + (size_t)n * HW * 100;
    // scatter C fragments: row m = l4*4+reg, col = nt*16+l15
#pragma unroll
    for (int nt = 0; nt < 7; ++nt) {
        f32x4 v = acc[nt];
#pragma unroll
        for (int reg = 0; reg < 4; ++reg)
            smE[(l4 * 4 + reg) * EPI_PAD + nt * 16 + l15] = v[reg];
    }
    // per-lane softmax: lane -> (px = lane>>2, q = lane&3)
    {
        int px = lane >> 2, q = lane & 3;
        float* row = smE + px * EPI_PAD;
        float v[NK], mx = -1e30f;
#pragma unroll
        for (int k = 0; k < NK; ++k) {
            v[k] = row[4 * k + q] + sbias[4 * k + q];
            mx = fmaxf(mx, v[k]);
        }
        float ssum = 0.f;
#pragma unroll
        for (int k = 0; k < NK; ++k) { v[k] = __expf(v[k] - mx); ssum += v[k]; }
        float inv = 1.0f / ssum;
#pragma unroll
        for (int k = 0; k < NK; ++k) row[4 * k + q] = v[k] * inv;
    }
    // coalesced write-out: 16 px x 25 float4 per wave
#pragma unroll
    for (int i = 0; i < 7; ++i) {
        int idx = i * 64 + lane;                 // 400 slots
        if (idx < 400) {
            int px = idx / 25, f4 = idx % 25;
            int rr = 2 * wv + (px >> 3), cc = px & 7;
            size_t p = (size_t)(h0 + rr) * 64 + (w0 + cc);
            *(float4*)(maskn + p * 100 + f4 * 4) =
                *(const float4*)(smE + px * EPI_PAD + f4 * 4);
        }
    }
}

// ---------------------------------------------------------------------------
// Kernel 3: CARAFE reassembly, LDS-staged + c-vectorized.
// Block: input tile 16w x 4h, 128 channels (cgrp), 256 thr = 16wx x 4py x 4c4.
// LDS x layout: [h(8)][w(20)] records of 16c (padded to 20 floats), dbuf.
// Per tap: 1 ds_read_b128 (4 c) -> 16 FMA (4c x 4 outputs). Grid 512 = 2/CU.
#define XREC    20                    // floats per px record
#define XBUF    (160 * XREC)          // 3200 floats per buffer
__global__ __launch_bounds__(256, 2) void k_reassemble(const float* __restrict__ x,
        const float* __restrict__ mask, float* __restrict__ out) {
    __shared__ float xs[2 * XBUF];    // 25.6 KB

    int n = blockIdx.z;
    int cgrp = blockIdx.y;            // 0/1 -> channels 0..127 / 128..255
    int tile = blockIdx.x;
    int tx = tile & 3, ty = tile >> 2;
    int w0 = tx * 16, h0 = ty * 4;
    int tid = threadIdx.x;
    int wx = tid & 15, py = (tid >> 4) & 3, c4 = tid >> 6;
    int c0 = cgrp * 128;

    // ---- load this thread's 25 mask float4s (contiguous per px) ----
    int p = (h0 + py) * W_DIM + (w0 + wx);
    const float* mp = mask + ((size_t)n * HW + p) * 100;
    f32x4 m[NK];
#pragma unroll
    for (int k = 0; k < NK; ++k) m[k] = *(const f32x4*)(mp + 4 * k);

    // ---- stage helpers ----
    const float* xn = x + (size_t)n * C_IN * HW;
    float2 v[5];
    int sc_l[5], sh[5], sseg[5];
#pragma unroll
    for (int i = 0; i < 5; ++i) {
        int slot = i * 256 + tid;                // 1280 slots = 16c x 8h x 10seg
        sc_l[i] = slot / 80;
        int rem = slot % 80;
        sh[i] = rem / 10; sseg[i] = rem % 10;
    }
    auto load_chunk = [&](int cb) {
#pragma unroll
        for (int i = 0; i < 5; ++i) {
            int gh = h0 - 2 + sh[i], gw = w0 - 2 + sseg[i] * 2;
            float2 t = make_float2(0.f, 0.f);
            if ((unsigned)gh < 64u && (unsigned)gw < 64u)
                t = *(const float2*)(xn + (size_t)(cb + sc_l[i]) * HW + gh * W_DIM + gw);
            v[i] = t;
        }
    };
    auto write_chunk = [&](int buf) {
        float* dst = xs + buf * XBUF;
#pragma unroll
        for (int i = 0; i < 5; ++i) {
            int a = (sh[i] * XREC + sseg[i] * 2) * XREC + sc_l[i];
            dst[a] = v[i].x;
            dst[a + XREC] = v[i].y;
        }
    };

    load_chunk(c0);
    write_chunk(0);
    __syncthreads();

    int base = ((py * XREC) + wx) * XREC + c4 * 4;   // float offset of (py,wx,c4*4)
    for (int ch = 0; ch < 8; ++ch) {
        if (ch < 7) load_chunk(c0 + (ch + 1) * 16);

        float acc[4][4];
#pragma unroll
        for (int a = 0; a < 4; ++a)
#pragma unroll
            for (int o = 0; o < 4; ++o) acc[a][o] = 0.f;

        const float* buf = xs + (ch & 1) * XBUF;
#pragma unroll
        for (int di = 0; di < 5; ++di)
#pragma unroll
            for (int dj = 0; dj < 5; ++dj) {
                f32x4 xv = *(const f32x4*)(buf + base + (di * XREC + dj) * XREC);
                f32x4 mk = m[di * 5 + dj];
#pragma unroll
                for (int a = 0; a < 4; ++a)
#pragma unroll
                    for (int o = 0; o < 4; ++o)
                        acc[a][o] = fmaf(xv[a], mk[o], acc[a][o]);
            }

        if (ch < 7) write_chunk((ch + 1) & 1);
        __syncthreads();

        int cb = c0 + ch * 16 + c4 * 4;
#pragma unroll
        for (int a = 0; a < 4; ++a) {
            float* ob = out + (((size_t)n * C_IN + cb + a) * 128 + 2 * (h0 + py)) * 128
                            + 2 * (w0 + wx);
#pragma unroll
            for (int i = 0; i < 2; ++i)
                *(float2*)(ob + i * 128) = make_float2(acc[a][i * 2], acc[a][i * 2 + 1]);
        }
    }
}

// ---------------------------------------------------------------------------
extern "C" void kernel_launch(void* const* d_in, const int* in_sizes, int n_in,
                              void* d_out, int out_size, void* d_ws, size_t ws_size,
                              hipStream_t stream) {
    const float* x      = (const float*)d_in[0];
    const float* w_comp = (const float*)d_in[1];
    const float* b_comp = (const float*)d_in[2];
    const float* w_enc  = (const float*)d_in[3];
    const float* b_enc  = (const float*)d_in[4];
    float* out = (float*)d_out;
    unsigned char* ws = (unsigned char*)d_ws;

    unsigned short* compb = (unsigned short*)(ws);              // 2,097,152 B
    unsigned short* wtb   = (unsigned short*)(ws + 2097152);    //   129,024 B
    float*          mask  = (float*)(ws + 2097152 + 129024);    // 6,553,600 B  [n][p][100]

    hipLaunchKernelGGL(k_wtrans,     dim3(252),      dim3(256), 0, stream, w_enc, wtb);
    hipLaunchKernelGGL(k_compress,   dim3(64, 4),    dim3(256), 0, stream, x, w_comp, b_comp, compb);
    hipLaunchKernelGGL(k_enc_mfma,   dim3(64, 4),    dim3(256), 0, stream, compb, wtb, b_enc, mask);
    hipLaunchKernelGGL(k_reassemble, dim3(64, 2, 4), dim3(256), 0, stream, x, mask, out);
}

// Round 4
// 169.891 us; speedup vs baseline: 2.9676x; 1.0546x over previous
//
#include <hip/hip_runtime.h>

#define HW      4096      // 64*64
#define W_DIM   64
#define C_IN    256
#define C_COMP  64
#define NK      25        // 5x5 taps
#define NQ      112       // kq padded 100 -> 112

typedef __bf16 bf16x8 __attribute__((ext_vector_type(8)));
typedef float  f32x4  __attribute__((ext_vector_type(4)));

static __device__ __forceinline__ unsigned short f2bf(float f) {
    unsigned x = __float_as_uint(f);
    unsigned r = (x + 0x7fffu + ((x >> 16) & 1u)) >> 16;   // RNE
    return (unsigned short)r;
}

// ---------------------------------------------------------------------------
// Kernel 0: weight prep.
//  wtb[tap][kq=112 (zero-pad)][c=64] bf16   (encoder weights, B-side stage 2)
//  wct[cc=64][c=256] bf16                    (compress weights, B-side stage 1)
__global__ __launch_bounds__(256) void k_prep(const float* __restrict__ wenc,
                                              const float* __restrict__ wcomp,
                                              unsigned short* __restrict__ wtb,
                                              unsigned short* __restrict__ wct) {
    int idx = blockIdx.x * 256 + threadIdx.x;   // 64512 + 16384 = 80896
    if (idx < 64512) {
        int c = idx & 63;
        int t2 = idx >> 6;
        int kq = t2 % NQ;
        int tap = t2 / NQ;
        float v = (kq < 100) ? wenc[(kq * 64 + c) * 9 + tap] : 0.0f;
        wtb[idx] = f2bf(v);
    } else if (idx < 80896) {
        int j = idx - 64512;                    // w_comp is [cc][c] contiguous
        wct[j] = f2bf(wcomp[j]);
    }
}

// ---------------------------------------------------------------------------
// Kernel 1 (fused): in-block compress (MFMA) -> LDS comp -> 3x3 encoder MFMA
// -> fused pixel-shuffle softmax. 8x8 px tiles, grid (64, 4).
//
// Phase 1 GEMM: M=128 halo-px (10x10 used), N=64 cc, K=256 c.
//   A: x transposed to LDS [px][32c] bf16, 80 B records, 8 K-chunks.
//   B: wct fragments straight from global (L2-resident).
//   D (+b_comp, zeroed outside image) -> comp LDS records [px][cc], 144 B.
// Phase 2: R3 encoder GEMM (M=64 px, N=112 kq, K=576) + softmax epilogue.
// mask output layout: [n][p][kq=100].
#define CSTRIDE 144          // bytes per px comp record (64c bf16 + 8 pad)
#define SB_OFF  14400        // 100 px * 144
#define EPI_OFF 30528        // SB_OFF + 112*144
#define A_OFF   30528        // phase-1 A region overlays epilogue region
#define AREC    80           // bytes per px row in A (32c bf16 + 16 pad)
#define EPI_PAD 116          // floats per px row (100 used, %4==0)
__global__ __launch_bounds__(256) void k_enc_fused(
        const float* __restrict__ x,
        const unsigned short* __restrict__ wct,
        const float* __restrict__ bcomp,
        const unsigned short* __restrict__ wtb,
        const float* __restrict__ benc,
        float* __restrict__ mask) {
    __shared__ __align__(16) unsigned char smem[60224];
    __shared__ float sbias[NQ];
    __shared__ float sbc[64];

    int n = blockIdx.y;
    int tile = blockIdx.x;                       // 64 tiles of 8x8
    int h0 = (tile >> 3) * 8, w0 = (tile & 7) * 8;
    int tid = threadIdx.x;
    int wv = tid >> 6, lane = tid & 63;
    int l15 = lane & 15, l4 = lane >> 4;

    if (tid < NQ) sbias[tid] = (tid < 100) ? benc[tid] : 0.0f;
    if (tid < 64) sbc[tid] = bcomp[tid];

    // zero A rows 100..127 once (never rewritten by staging)
    {
        unsigned* az = (unsigned*)(smem + A_OFF + 100 * AREC);
        for (int i = tid; i < 560; i += 256) az[i] = 0u;
    }

    // ---- precompute the 7 staging tasks per thread (1600 = 100px x 16 c-pairs)
    const float* xn = x + (size_t)n * C_IN * HW;
    int t_ghw[7], t_lds[7], t_c[7];
    bool t_val[7], t_img[7];
#pragma unroll
    for (int t = 0; t < 7; ++t) {
        int slot = t * 256 + tid;
        t_val[t] = slot < 1600;
        int s = t_val[t] ? slot : 0;
        int c2 = s / 100, px = s % 100;
        int gh = h0 + px / 10 - 1, gw = w0 + px % 10 - 1;
        t_img[t] = ((unsigned)gh < 64u) && ((unsigned)gw < 64u);
        t_ghw[t] = gh * W_DIM + gw;
        t_lds[t] = px * AREC + c2 * 4;
        t_c[t] = c2 * 2;
    }

    // ---- Phase 1: compress GEMM over 8 K-chunks of 32 c ----
    f32x4 acc1[2][4];
#pragma unroll
    for (int mt = 0; mt < 2; ++mt)
#pragma unroll
        for (int nt = 0; nt < 4; ++nt) acc1[mt][nt] = (f32x4){0.f, 0.f, 0.f, 0.f};

    for (int ck = 0; ck < 8; ++ck) {
        __syncthreads();                         // A buffer free (prev mfma done)
#pragma unroll
        for (int t = 0; t < 7; ++t) {
            if (t_val[t]) {
                float a0 = 0.f, a1 = 0.f;
                if (t_img[t]) {
                    const float* xp = xn + (size_t)(ck * 32 + t_c[t]) * HW + t_ghw[t];
                    a0 = xp[0];
                    a1 = xp[HW];
                }
                unsigned pack = (unsigned)f2bf(a0) | ((unsigned)f2bf(a1) << 16);
                *(unsigned*)(smem + A_OFF + t_lds[t]) = pack;
            }
        }
        __syncthreads();
        bf16x8 bfr[4], af[2];
#pragma unroll
        for (int nt = 0; nt < 4; ++nt)
            bfr[nt] = *(const bf16x8*)(wct + (size_t)(nt * 16 + l15) * 256 + ck * 32 + l4 * 8);
#pragma unroll
        for (int mt = 0; mt < 2; ++mt)
            af[mt] = *(const bf16x8*)(smem + A_OFF +
                     (size_t)((2 * wv + mt) * 16 + l15) * AREC + l4 * 16);
#pragma unroll
        for (int mt = 0; mt < 2; ++mt)
#pragma unroll
            for (int nt = 0; nt < 4; ++nt)
                acc1[mt][nt] = __builtin_amdgcn_mfma_f32_16x16x32_bf16(
                        af[mt], bfr[nt], acc1[mt][nt], 0, 0, 0);
    }
    __syncthreads();                             // last A-frag reads done

    // ---- write comp records: D1 + b_comp, zeroed outside image ----
#pragma unroll
    for (int mt = 0; mt < 2; ++mt) {
        int pxb = (2 * wv + mt) * 16 + l4 * 4;
#pragma unroll
        for (int reg = 0; reg < 4; ++reg) {
            int px = pxb + reg;
            if (px < 100) {
                int gh = h0 + px / 10 - 1, gw = w0 + px % 10 - 1;
                bool img = ((unsigned)gh < 64u) && ((unsigned)gw < 64u);
#pragma unroll
                for (int nt = 0; nt < 4; ++nt) {
                    int cc = nt * 16 + l15;
                    float v = img ? (acc1[mt][nt][reg] + sbc[cc]) : 0.0f;
                    *(unsigned short*)(smem + (size_t)px * CSTRIDE + cc * 2) = f2bf(v);
                }
            }
        }
    }
    // ---- stage B panel for tap 0 (region disjoint from comp/A) ----
    {
        const uint4* bsrc = (const uint4*)(wtb);
#pragma unroll
        for (int pass = 0; pass < 4; ++pass) {
            int slot = pass * 256 + tid;         // 112*8 = 896 slots
            if (slot < 896) {
                int kq = slot >> 3, j = slot & 7;
                *(uint4*)(smem + SB_OFF + kq * CSTRIDE + j * 16) = bsrc[slot];
            }
        }
    }
    __syncthreads();

    // ---- Phase 2: encoder GEMM ----
    f32x4 acc[7];
#pragma unroll
    for (int nt = 0; nt < 7; ++nt) acc[nt] = (f32x4){0.f, 0.f, 0.f, 0.f};

    int r_t = 2 * wv + (l15 >> 3);               // tile-local row of A fragment
    int cl  = l15 & 7;

    for (int tap = 0; tap < 9; ++tap) {
        uint4 pre[4];
        if (tap < 8) {
            const uint4* bsrc = (const uint4*)(wtb + (size_t)(tap + 1) * NQ * 64);
#pragma unroll
            for (int pass = 0; pass < 4; ++pass) {
                int slot = pass * 256 + tid;
                if (slot < 896) pre[pass] = bsrc[slot];
            }
        }
        int ti = tap / 3, tj = tap % 3;
        int apx = (r_t + ti) * 10 + (cl + tj);   // halo px index (origin -1 baked)
#pragma unroll
        for (int ck = 0; ck < 2; ++ck) {
            int koff = (ck * 32 + l4 * 8) * 2;
            bf16x8 af = *(const bf16x8*)(smem + (size_t)apx * CSTRIDE + koff);
            bf16x8 bfr[7];
#pragma unroll
            for (int nt = 0; nt < 7; ++nt)
                bfr[nt] = *(const bf16x8*)(smem + SB_OFF +
                        (size_t)(nt * 16 + l15) * CSTRIDE + koff);
#pragma unroll
            for (int nt = 0; nt < 7; ++nt)
                acc[nt] = __builtin_amdgcn_mfma_f32_16x16x32_bf16(
                        af, bfr[nt], acc[nt], 0, 0, 0);
        }
        __syncthreads();
        if (tap < 8) {
#pragma unroll
            for (int pass = 0; pass < 4; ++pass) {
                int slot = pass * 256 + tid;
                if (slot < 896) {
                    int kq = slot >> 3, j = slot & 7;
                    *(uint4*)(smem + SB_OFF + kq * CSTRIDE + j * 16) = pre[pass];
                }
            }
        }
        __syncthreads();
    }

    // ---- epilogue: per-wave region (overlays dead A region) ----
    float* smE = (float*)(smem + EPI_OFF) + (size_t)wv * 16 * EPI_PAD;
    float* maskn = mask + (size_t)n * HW * 100;
#pragma unroll
    for (int nt = 0; nt < 7; ++nt) {
        f32x4 v = acc[nt];
#pragma unroll
        for (int reg = 0; reg < 4; ++reg)
            smE[(l4 * 4 + reg) * EPI_PAD + nt * 16 + l15] = v[reg];
    }
    {
        int px = lane >> 2, q = lane & 3;
        float* row = smE + px * EPI_PAD;
        float v[NK], mx = -1e30f;
#pragma unroll
        for (int k = 0; k < NK; ++k) {
            v[k] = row[4 * k + q] + sbias[4 * k + q];
            mx = fmaxf(mx, v[k]);
        }
        float ssum = 0.f;
#pragma unroll
        for (int k = 0; k < NK; ++k) { v[k] = __expf(v[k] - mx); ssum += v[k]; }
        float inv = 1.0f / ssum;
#pragma unroll
        for (int k = 0; k < NK; ++k) row[4 * k + q] = v[k] * inv;
    }
#pragma unroll
    for (int i = 0; i < 7; ++i) {
        int idx = i * 64 + lane;                 // 400 slots
        if (idx < 400) {
            int px = idx / 25, f4 = idx % 25;
            int rr = 2 * wv + (px >> 3), cc = px & 7;
            size_t p = (size_t)(h0 + rr) * 64 + (w0 + cc);
            *(float4*)(maskn + p * 100 + f4 * 4) =
                *(const float4*)(smE + px * EPI_PAD + f4 * 4);
        }
    }
}

// ---------------------------------------------------------------------------
// Kernel 2: CARAFE reassembly, LDS-staged + c-vectorized (unchanged from R3).
#define XREC    20                    // floats per px record
#define XBUF    (160 * XREC)          // 3200 floats per buffer
__global__ __launch_bounds__(256, 2) void k_reassemble(const float* __restrict__ x,
        const float* __restrict__ mask, float* __restrict__ out) {
    __shared__ float xs[2 * XBUF];    // 25.6 KB

    int n = blockIdx.z;
    int cgrp = blockIdx.y;
    int tile = blockIdx.x;
    int tx = tile & 3, ty = tile >> 2;
    int w0 = tx * 16, h0 = ty * 4;
    int tid = threadIdx.x;
    int wx = tid & 15, py = (tid >> 4) & 3, c4 = tid >> 6;
    int c0 = cgrp * 128;

    int p = (h0 + py) * W_DIM + (w0 + wx);
    const float* mp = mask + ((size_t)n * HW + p) * 100;
    f32x4 m[NK];
#pragma unroll
    for (int k = 0; k < NK; ++k) m[k] = *(const f32x4*)(mp + 4 * k);

    const float* xn = x + (size_t)n * C_IN * HW;
    float2 v[5];
    int sc_l[5], sh[5], sseg[5];
#pragma unroll
    for (int i = 0; i < 5; ++i) {
        int slot = i * 256 + tid;                // 1280 slots = 16c x 8h x 10seg
        sc_l[i] = slot / 80;
        int rem = slot % 80;
        sh[i] = rem / 10; sseg[i] = rem % 10;
    }
    auto load_chunk = [&](int cb) {
#pragma unroll
        for (int i = 0; i < 5; ++i) {
            int gh = h0 - 2 + sh[i], gw = w0 - 2 + sseg[i] * 2;
            float2 t = make_float2(0.f, 0.f);
            if ((unsigned)gh < 64u && (unsigned)gw < 64u)
                t = *(const float2*)(xn + (size_t)(cb + sc_l[i]) * HW + gh * W_DIM + gw);
            v[i] = t;
        }
    };
    auto write_chunk = [&](int buf) {
        float* dst = xs + buf * XBUF;
#pragma unroll
        for (int i = 0; i < 5; ++i) {
            int a = (sh[i] * XREC + sseg[i] * 2) * XREC + sc_l[i];
            dst[a] = v[i].x;
            dst[a + XREC] = v[i].y;
        }
    };

    load_chunk(c0);
    write_chunk(0);
    __syncthreads();

    int base = ((py * XREC) + wx) * XREC + c4 * 4;
    for (int ch = 0; ch < 8; ++ch) {
        if (ch < 7) load_chunk(c0 + (ch + 1) * 16);

        float acc[4][4];
#pragma unroll
        for (int a = 0; a < 4; ++a)
#pragma unroll
            for (int o = 0; o < 4; ++o) acc[a][o] = 0.f;

        const float* buf = xs + (ch & 1) * XBUF;
#pragma unroll
        for (int di = 0; di < 5; ++di)
#pragma unroll
            for (int dj = 0; dj < 5; ++dj) {
                f32x4 xv = *(const f32x4*)(buf + base + (di * XREC + dj) * XREC);
                f32x4 mk = m[di * 5 + dj];
#pragma unroll
                for (int a = 0; a < 4; ++a)
#pragma unroll
                    for (int o = 0; o < 4; ++o)
                        acc[a][o] = fmaf(xv[a], mk[o], acc[a][o]);
            }

        if (ch < 7) write_chunk((ch + 1) & 1);
        __syncthreads();

        int cb = c0 + ch * 16 + c4 * 4;
#pragma unroll
        for (int a = 0; a < 4; ++a) {
            float* ob = out + (((size_t)n * C_IN + cb + a) * 128 + 2 * (h0 + py)) * 128
                            + 2 * (w0 + wx);
#pragma unroll
            for (int i = 0; i < 2; ++i)
                *(float2*)(ob + i * 128) = make_float2(acc[a][i * 2], acc[a][i * 2 + 1]);
        }
    }
}

// ---------------------------------------------------------------------------
extern "C" void kernel_launch(void* const* d_in, const int* in_sizes, int n_in,
                              void* d_out, int out_size, void* d_ws, size_t ws_size,
                              hipStream_t stream) {
    const float* x      = (const float*)d_in[0];
    const float* w_comp = (const float*)d_in[1];
    const float* b_comp = (const float*)d_in[2];
    const float* w_enc  = (const float*)d_in[3];
    const float* b_enc  = (const float*)d_in[4];
    float* out = (float*)d_out;
    unsigned char* ws = (unsigned char*)d_ws;

    unsigned short* wtb  = (unsigned short*)(ws);              // 129,024 B
    unsigned short* wct  = (unsigned short*)(ws + 129024);     //  32,768 B
    float*          mask = (float*)(ws + 161792);              // 6,553,600 B  [n][p][100]

    hipLaunchKernelGGL(k_prep,       dim3(316),      dim3(256), 0, stream,
                       w_enc, w_comp, wtb, wct);
    hipLaunchKernelGGL(k_enc_fused,  dim3(64, 4),    dim3(256), 0, stream,
                       x, wct, b_comp, wtb, b_enc, mask);
    hipLaunchKernelGGL(k_reassemble, dim3(64, 2, 4), dim3(256), 0, stream, x, mask, out);
}

// Round 5
// 143.049 us; speedup vs baseline: 3.5244x; 1.1876x over previous
//
#include <hip/hip_runtime.h>

#define HW      4096      // 64*64
#define W_DIM   64
#define C_IN    256
#define NK      25        // 5x5 taps
#define NQ      112       // kq padded 100 -> 112

typedef __bf16 bf16x4 __attribute__((ext_vector_type(4)));
typedef __bf16 bf16x8 __attribute__((ext_vector_type(8)));
typedef float  f32x4  __attribute__((ext_vector_type(4)));
typedef float  f32x2  __attribute__((ext_vector_type(2)));

static __device__ __forceinline__ unsigned short f2bf(float f) {
    unsigned x = __float_as_uint(f);
    return (unsigned short)((x + 0x7fffu + ((x >> 16) & 1u)) >> 16);   // RNE
}
static __device__ __forceinline__ float bflo2f(unsigned u) { return __uint_as_float(u << 16); }
static __device__ __forceinline__ float bfhi2f(unsigned u) { return __uint_as_float(u & 0xffff0000u); }

// ---------------------------------------------------------------------------
// Kernel 0: weight prep.
//  wtb[tap][kq=112 zero-pad][c=64] bf16   (encoder B panels)
//  wct[cc=64][c=256] bf16                 (compress B)
__global__ __launch_bounds__(256) void k_prep(const float* __restrict__ wenc,
                                              const float* __restrict__ wcomp,
                                              unsigned short* __restrict__ wtb,
                                              unsigned short* __restrict__ wct) {
    int idx = blockIdx.x * 256 + threadIdx.x;   // 64512 + 16384 = 80896
    if (idx < 64512) {
        int c = idx & 63;
        int t2 = idx >> 6;
        int kq = t2 % NQ;
        int tap = t2 / NQ;
        float v = (kq < 100) ? wenc[(kq * 64 + c) * 9 + tap] : 0.0f;
        wtb[idx] = f2bf(v);
    } else if (idx < 80896) {
        int j = idx - 64512;
        wct[j] = f2bf(wcomp[j]);
    }
}

// ---------------------------------------------------------------------------
// Kernel 1: MFMA 1x1 compress. GEMM M=64 px (contig p), N=64 cc, K=256 c.
// A staged coalesced (256B runs), LDS rows 260 u16 (130 dw = 2 mod 32: free).
// Zero barriers in K-loop. Out: comp[n][p][cc=64] bf16 (+bias).
__global__ __launch_bounds__(256) void k_compress(const float* __restrict__ x,
        const unsigned short* __restrict__ wct, const float* __restrict__ bcomp,
        unsigned short* __restrict__ comp) {
    __shared__ unsigned short As[64 * 260];     // 33,280 B
    __shared__ unsigned short Bs[64 * 260];     // 33,280 B
    __shared__ float sbc[64];
    int n = blockIdx.y, p0 = blockIdx.x * 64;
    int tid = threadIdx.x, wv = tid >> 6, lane = tid & 63;
    int l15 = lane & 15, l4 = lane >> 4;
    if (tid < 64) sbc[tid] = bcomp[tid];

    const float* xp = x + (size_t)n * C_IN * HW + p0;
#pragma unroll
    for (int s = 0; s < 32; ++s) {              // A: 128 c-pairs x 64 px
        int cp = s * 4 + wv;                    // wave-uniform c-pair
        float a = xp[(size_t)(2 * cp) * HW + lane];
        float b = xp[(size_t)(2 * cp + 1) * HW + lane];
        unsigned pk = (unsigned)f2bf(a) | ((unsigned)f2bf(b) << 16);
        *(unsigned*)(As + lane * 260 + cp * 2) = pk;
    }
    const unsigned* wsrc = (const unsigned*)wct;
#pragma unroll
    for (int s = 0; s < 32; ++s) {              // B: 64 cc x 128 u32
        int slot = s * 256 + tid;
        int cc = slot >> 7, c2 = slot & 127;
        *(unsigned*)(Bs + cc * 260 + c2 * 2) = wsrc[cc * 128 + c2];
    }
    __syncthreads();

    f32x4 acc[4];
#pragma unroll
    for (int nt = 0; nt < 4; ++nt) acc[nt] = (f32x4){0.f, 0.f, 0.f, 0.f};
#pragma unroll
    for (int ck = 0; ck < 8; ++ck) {
        int ko = ck * 32 + l4 * 8;              // u16 offset in row
        bf16x4 alo = *(const bf16x4*)(As + (wv * 16 + l15) * 260 + ko);
        bf16x4 ahi = *(const bf16x4*)(As + (wv * 16 + l15) * 260 + ko + 4);
        bf16x8 af = __builtin_shufflevector(alo, ahi, 0, 1, 2, 3, 4, 5, 6, 7);
#pragma unroll
        for (int nt = 0; nt < 4; ++nt) {
            bf16x4 blo = *(const bf16x4*)(Bs + (nt * 16 + l15) * 260 + ko);
            bf16x4 bhi = *(const bf16x4*)(Bs + (nt * 16 + l15) * 260 + ko + 4);
            bf16x8 bfr = __builtin_shufflevector(blo, bhi, 0, 1, 2, 3, 4, 5, 6, 7);
            acc[nt] = __builtin_amdgcn_mfma_f32_16x16x32_bf16(af, bfr, acc[nt], 0, 0, 0);
        }
    }
    unsigned short* op = comp + ((size_t)n * HW + p0 + wv * 16 + l4 * 4) * 64;
#pragma unroll
    for (int reg = 0; reg < 4; ++reg)
#pragma unroll
        for (int nt = 0; nt < 4; ++nt) {
            int cc = nt * 16 + l15;
            op[(size_t)reg * 64 + cc] = f2bf(acc[nt][reg] + sbc[cc]);
        }
}

// ---------------------------------------------------------------------------
// Kernel 2: MFMA 3x3 encoder (64->100) + fused softmax. 8x8 tiles, grid (64,4).
// comp halo staged coalesced; B double-buffered, ONE barrier per tap.
// All LDS records 136 B (34 dw = 2 mod 32 -> 2-way free), b64 reads.
#define CREC    136
#define SB0     13600                // 100 px * 136
#define BSTRIDE 15232                // 112 * 136
#define EPI_PAD 116
__global__ __launch_bounds__(256) void k_enc(
        const unsigned short* __restrict__ comp,
        const unsigned short* __restrict__ wtb,
        const float* __restrict__ benc,
        float* __restrict__ mask) {
    __shared__ __align__(16) unsigned char smem[SB0 + 2 * BSTRIDE];   // 44,064 B
    __shared__ float sbias[NQ];
    int n = blockIdx.y, tile = blockIdx.x;
    int h0 = (tile >> 3) * 8, w0 = (tile & 7) * 8;
    int tid = threadIdx.x, wv = tid >> 6, lane = tid & 63;
    int l15 = lane & 15, l4 = lane >> 4;
    if (tid < NQ) sbias[tid] = (tid < 100) ? benc[tid] : 0.0f;

    // stage comp halo: 100 px x 128 B, zero OOB (conv zero-pad)
    const uint4* csrc = (const uint4*)(comp + (size_t)n * HW * 64);
#pragma unroll
    for (int pass = 0; pass < 4; ++pass) {
        int s = pass * 256 + tid;               // 800 slots
        if (s < 800) {
            int px = s >> 3, j = s & 7;
            int gh = h0 + px / 10 - 1, gw = w0 + px % 10 - 1;
            uint4 v = make_uint4(0u, 0u, 0u, 0u);
            if ((unsigned)gh < 64u && (unsigned)gw < 64u)
                v = csrc[(size_t)(gh * 64 + gw) * 8 + j];
            *(uint2*)(smem + px * CREC + j * 16)     = make_uint2(v.x, v.y);
            *(uint2*)(smem + px * CREC + j * 16 + 8) = make_uint2(v.z, v.w);
        }
    }
    // stage B(0) -> buf0; preload B(1) -> regs
    {
        const uint4* bs = (const uint4*)wtb;
#pragma unroll
        for (int pass = 0; pass < 4; ++pass) {
            int s = pass * 256 + tid;           // 896 slots
            if (s < 896) {
                uint4 v = bs[s];
                int kq = s >> 3, j = s & 7;
                *(uint2*)(smem + SB0 + kq * CREC + j * 16)     = make_uint2(v.x, v.y);
                *(uint2*)(smem + SB0 + kq * CREC + j * 16 + 8) = make_uint2(v.z, v.w);
            }
        }
    }
    uint4 pre[4];
    {
        const uint4* bs = (const uint4*)(wtb + (size_t)1 * NQ * 64);
#pragma unroll
        for (int pass = 0; pass < 4; ++pass) {
            int s = pass * 256 + tid;
            if (s < 896) pre[pass] = bs[s];
        }
    }

    f32x4 acc[7];
#pragma unroll
    for (int nt = 0; nt < 7; ++nt) acc[nt] = (f32x4){0.f, 0.f, 0.f, 0.f};
    int r_t = 2 * wv + (l15 >> 3), cl = l15 & 7;

    for (int tap = 0; tap < 9; ++tap) {
        __syncthreads();                        // separates buf reads(t-1) from writes(t+1)
        if (tap < 8) {
            unsigned char* nbuf = smem + SB0 + ((tap + 1) & 1) * BSTRIDE;
#pragma unroll
            for (int pass = 0; pass < 4; ++pass) {
                int s = pass * 256 + tid;
                if (s < 896) {
                    int kq = s >> 3, j = s & 7;
                    *(uint2*)(nbuf + kq * CREC + j * 16)     = make_uint2(pre[pass].x, pre[pass].y);
                    *(uint2*)(nbuf + kq * CREC + j * 16 + 8) = make_uint2(pre[pass].z, pre[pass].w);
                }
            }
            if (tap < 7) {
                const uint4* bs = (const uint4*)(wtb + (size_t)(tap + 2) * NQ * 64);
#pragma unroll
                for (int pass = 0; pass < 4; ++pass) {
                    int s = pass * 256 + tid;
                    if (s < 896) pre[pass] = bs[s];
                }
            }
        }
        int ti = tap / 3, tj = tap % 3;
        int apx = (r_t + ti) * 10 + cl + tj;
        const unsigned char* cbuf = smem + SB0 + (tap & 1) * BSTRIDE;
#pragma unroll
        for (int ck = 0; ck < 2; ++ck) {
            int ko = ck * 64 + l4 * 16;         // byte offset in record
            bf16x4 alo = *(const bf16x4*)(smem + apx * CREC + ko);
            bf16x4 ahi = *(const bf16x4*)(smem + apx * CREC + ko + 8);
            bf16x8 af = __builtin_shufflevector(alo, ahi, 0, 1, 2, 3, 4, 5, 6, 7);
#pragma unroll
            for (int nt = 0; nt < 7; ++nt) {
                bf16x4 blo = *(const bf16x4*)(cbuf + (nt * 16 + l15) * CREC + ko);
                bf16x4 bhi = *(const bf16x4*)(cbuf + (nt * 16 + l15) * CREC + ko + 8);
                bf16x8 bfr = __builtin_shufflevector(blo, bhi, 0, 1, 2, 3, 4, 5, 6, 7);
                acc[nt] = __builtin_amdgcn_mfma_f32_16x16x32_bf16(af, bfr, acc[nt], 0, 0, 0);
            }
        }
    }
    __syncthreads();                            // B buffers dead; epilogue overlays

    float* smE = (float*)(smem + SB0) + (size_t)wv * 16 * EPI_PAD;
    float* maskn = mask + (size_t)n * HW * 100;
#pragma unroll
    for (int nt = 0; nt < 7; ++nt) {
        f32x4 v = acc[nt];
#pragma unroll
        for (int reg = 0; reg < 4; ++reg)
            smE[(l4 * 4 + reg) * EPI_PAD + nt * 16 + l15] = v[reg];
    }
    {
        int spx = lane >> 2, q = lane & 3;
        float* row = smE + spx * EPI_PAD;
        float v[NK], mx = -1e30f;
#pragma unroll
        for (int k = 0; k < NK; ++k) {
            v[k] = row[4 * k + q] + sbias[4 * k + q];
            mx = fmaxf(mx, v[k]);
        }
        float ssum = 0.f;
#pragma unroll
        for (int k = 0; k < NK; ++k) { v[k] = __expf(v[k] - mx); ssum += v[k]; }
        float inv = 1.0f / ssum;
#pragma unroll
        for (int k = 0; k < NK; ++k) row[4 * k + q] = v[k] * inv;
    }
#pragma unroll
    for (int i = 0; i < 7; ++i) {
        int idx = i * 64 + lane;                // 400 slots
        if (idx < 400) {
            int spx = idx / 25, f4 = idx % 25;
            int rr = 2 * wv + (spx >> 3), cc2 = spx & 7;
            size_t p = (size_t)(h0 + rr) * 64 + (w0 + cc2);
            *(float4*)(maskn + p * 100 + f4 * 4) =
                *(const float4*)(smE + spx * EPI_PAD + f4 * 4);
        }
    }
}

// ---------------------------------------------------------------------------
// Kernel 3: reassembly v3. 8x8 tile x 64 c, grid (64,4,4)=1024 blocks.
// Stage once (x f32 zero-padded, mask bf16), ONE barrier, then pure compute.
// xs stride 66 dw (2 mod 32: free, b64-aligned); ms stride 108 u16 (b64 ok).
#define XSTR 66
#define MSTR 108
__global__ __launch_bounds__(256, 3) void k_reassemble(const float* __restrict__ x,
        const float* __restrict__ mask, float* __restrict__ out) {
    __shared__ float xs[144 * XSTR];            // 38,016 B
    __shared__ unsigned short ms[64 * MSTR];    // 13,824 B
    int n = blockIdx.z, cg = blockIdx.y, tile = blockIdx.x;
    int h0 = (tile >> 3) * 8, w0 = (tile & 7) * 8;
    int c0 = cg * 64;
    int tid = threadIdx.x;

    const float* xb = x + ((size_t)n * C_IN + c0) * HW;
#pragma unroll
    for (int i = 0; i < 36; ++i) {              // 144 halo px x 64 c, zero OOB
        int s = i * 256 + tid;
        int c = s / 144, px = s % 144;
        int r = px / 12, cl = px % 12;
        int gh = h0 - 2 + r, gw = w0 - 2 + cl;
        float v = 0.f;
        if ((unsigned)gh < 64u && (unsigned)gw < 64u)
            v = xb[(size_t)c * HW + gh * W_DIM + gw];
        xs[px * XSTR + c] = v;
    }
    const float* mp = mask + (size_t)n * HW * 100;
#pragma unroll
    for (int i = 0; i < 25; ++i) {              // 64 px x 100 kq -> bf16 [px][kq]
        int s = i * 256 + tid;
        int px = s / 100, kq = s % 100;
        int gp = (h0 + (px >> 3)) * W_DIM + w0 + (px & 7);
        ms[px * MSTR + kq] = f2bf(mp[(size_t)gp * 100 + kq]);
    }
    __syncthreads();

    int px = tid & 63, cgl = tid >> 6;          // wave = 16-channel subgroup
    int wx = px & 7, hy = px >> 3;
    int cbase = cgl * 16;
    f32x4 acc[16];
#pragma unroll
    for (int u = 0; u < 16; ++u) acc[u] = (f32x4){0.f, 0.f, 0.f, 0.f};
    const unsigned short* mrow = ms + px * MSTR;
#pragma unroll
    for (int di = 0; di < 5; ++di)
#pragma unroll
        for (int dj = 0; dj < 5; ++dj) {
            int t = di * 5 + dj;
            uint2 mw = *(const uint2*)(mrow + t * 4);
            f32x4 m4;
            m4[0] = bflo2f(mw.x); m4[1] = bfhi2f(mw.x);
            m4[2] = bflo2f(mw.y); m4[3] = bfhi2f(mw.y);
            const float* xrow = xs + ((hy + di) * 12 + wx + dj) * XSTR + cbase;
#pragma unroll
            for (int u2 = 0; u2 < 8; ++u2) {
                f32x2 xv = *(const f32x2*)(xrow + u2 * 2);
                acc[u2 * 2 + 0] += m4 * xv[0];
                acc[u2 * 2 + 1] += m4 * xv[1];
            }
        }
#pragma unroll
    for (int u = 0; u < 16; ++u) {
        float* ob = out + (((size_t)n * C_IN + c0 + cbase + u) * 128 + 2 * (h0 + hy)) * 128
                        + 2 * (w0 + wx);
        *(float2*)(ob)       = make_float2(acc[u][0], acc[u][1]);
        *(float2*)(ob + 128) = make_float2(acc[u][2], acc[u][3]);
    }
}

// ---------------------------------------------------------------------------
extern "C" void kernel_launch(void* const* d_in, const int* in_sizes, int n_in,
                              void* d_out, int out_size, void* d_ws, size_t ws_size,
                              hipStream_t stream) {
    const float* x      = (const float*)d_in[0];
    const float* w_comp = (const float*)d_in[1];
    const float* b_comp = (const float*)d_in[2];
    const float* w_enc  = (const float*)d_in[3];
    const float* b_enc  = (const float*)d_in[4];
    float* out = (float*)d_out;
    unsigned char* ws = (unsigned char*)d_ws;

    unsigned short* comp = (unsigned short*)(ws);              // 4*4096*64*2  = 2,097,152 B
    unsigned short* wtb  = (unsigned short*)(ws + 2097152);    // 9*112*64*2   =   129,024 B
    unsigned short* wct  = (unsigned short*)(ws + 2226176);    // 64*256*2     =    32,768 B
    float*          maskp = (float*)(ws + 2258944);            // 4*4096*100*4 = 6,553,600 B

    hipLaunchKernelGGL(k_prep,       dim3(316),      dim3(256), 0, stream,
                       w_enc, w_comp, wtb, wct);
    hipLaunchKernelGGL(k_compress,   dim3(64, 4),    dim3(256), 0, stream,
                       x, wct, b_comp, comp);
    hipLaunchKernelGGL(k_enc,        dim3(64, 4),    dim3(256), 0, stream,
                       comp, wtb, b_enc, maskp);
    hipLaunchKernelGGL(k_reassemble, dim3(64, 4, 4), dim3(256), 0, stream,
                       x, maskp, out);
}